// Round 18
// baseline (69.186 us; speedup 1.0000x reference)
//
#include <hip/hip_runtime.h>
#include <hip/hip_bf16.h>

typedef __attribute__((ext_vector_type(8))) short short8;
typedef __attribute__((ext_vector_type(4))) float f32x4;

#define M_TOTAL 131072
#define K_DIM 512
#define N_DIM 128
#define BM 128
#define BK 64
#define HALF 65536
#define GBLOCKS 1024
#define KSTEPS 8

// 64 bf16 = 128 B data + 16 B pad = 144 B rows
#define LSTRIDE 144
#define XTILE (BM * LSTRIDE)         // 18432 B
#define WTILE (N_DIM * LSTRIDE)      // 18432 B
// post-k-loop stash: 128 rows x 132 floats (528 B rows, 16B-aligned)
#define SSTRIDE 132

__device__ __forceinline__ short bf16_bits(float f) {
    __hip_bfloat16 h = __float2bfloat16(f);
    return __builtin_bit_cast(short, h);
}

__device__ __forceinline__ short8 cvt8(f32x4 a, f32x4 b) {
    short8 p;
    p[0] = bf16_bits(a[0]); p[1] = bf16_bits(a[1]);
    p[2] = bf16_bits(a[2]); p[3] = bf16_bits(a[3]);
    p[4] = bf16_bits(b[0]); p[5] = bf16_bits(b[1]);
    p[6] = bf16_bits(b[2]); p[7] = bf16_bits(b[3]);
    return p;
}

// ---------------- W -> W^T bf16 prep ----------------------------------------
__global__ void __launch_bounds__(256) wt_prep_kernel(
    const float* __restrict__ W, __hip_bfloat16* __restrict__ Wt)
{
    int idx = blockIdx.x * 256 + threadIdx.x;   // 65536 total
    int k = idx >> 7;        // 0..511
    int n = idx & 127;       // 0..127
    Wt[n * K_DIM + k] = __float2bfloat16(W[idx]);
}

// ---- fused: relu(x@W+b) + MMD; stash-gathered coalesced nt stores ---------
// R17 core; epilogue writes only the LDS stash, then a store phase re-reads
// the stash linearly and emits fully-coalesced f32x4 nontemporal stores
// (1 KB dense per wave-instruction); MMD overlaps the store latency.
__global__ void __launch_bounds__(512) gemm_relu_mmd_kernel(
    const float* __restrict__ x, const __hip_bfloat16* __restrict__ Wt,
    const float* __restrict__ bias, float* __restrict__ out,
    double* __restrict__ partials)
{
    __shared__ char pool[2 * XTILE + 2 * WTILE];   // 73728 B -> 2 blocks/CU
    char* xa = pool;                  // x tile t at pool + (t&1)*XTILE
    char* wb = pool + 2 * XTILE;      // W tile t at wb   + (t&1)*WTILE
    // post-k-loop aliases (whole pool dead after last barrier):
    float* stash = (float*)pool;              // [128][SSTRIDE] = 67584 B
    float* gsh   = (float*)(pool + 67584);    // 32 pair partials

    const int tid  = threadIdx.x;
    const int lane = tid & 63;
    const int wave = tid >> 6;          // 0..7: 4 row-groups x 2 col-groups
    const int wrow = (wave & 3) * 32;   // local rows wrow..wrow+31
    const int wcol = (wave >> 2) * 64;  // cols wcol..wcol+63
    const long blk = blockIdx.x;
    const long row0f = blk * 64;                 // first-half base
    const long row0s = (long)HALF + blk * 64;    // second-half base

    f32x4 acc[2][4];
#pragma unroll
    for (int m = 0; m < 2; ++m)
#pragma unroll
        for (int n = 0; n < 4; ++n) acc[m][n] = (f32x4)(0.0f);

    // staging: R10's proven pattern, run twice per tile (sub-stages s=0,1)
    const int sr  = tid >> 2;           // 0..127
    const int sby = (tid & 3) * 16;     // byte offset within 64B sub-window
    const long gr = (sr < 64) ? (row0f + sr) : (row0s + sr - 64);
    const float* xsrc = x + gr * (long)K_DIM + (tid & 3) * 8;
    const __hip_bfloat16* wsrc = Wt + (long)sr * K_DIM + (tid & 3) * 8;

    const int frow = lane & 15;
    const int kg   = (lane >> 4) * 8;

    f32x4 xr[2][2];   // [sub-stage][pair]
    short8 wr[2];

#define ISSUE(kt) do { \
        xr[0][0] = *(const f32x4*)(xsrc + (kt)); \
        xr[0][1] = *(const f32x4*)(xsrc + (kt) + 4); \
        xr[1][0] = *(const f32x4*)(xsrc + (kt) + 32); \
        xr[1][1] = *(const f32x4*)(xsrc + (kt) + 36); \
        wr[0] = *(const short8*)(wsrc + (kt)); \
        wr[1] = *(const short8*)(wsrc + (kt) + 32); \
    } while (0)

#define WRITE(xbuf, wbuf) do { \
        *(short8*)((xbuf) + sr * LSTRIDE + 0 * 64 + sby) = cvt8(xr[0][0], xr[0][1]); \
        *(short8*)((xbuf) + sr * LSTRIDE + 1 * 64 + sby) = cvt8(xr[1][0], xr[1][1]); \
        *(short8*)((wbuf) + sr * LSTRIDE + 0 * 64 + sby) = wr[0]; \
        *(short8*)((wbuf) + sr * LSTRIDE + 1 * 64 + sby) = wr[1]; \
    } while (0)

    // ---- prologue: stage tile 0 into buffer 0; tile 1's loads in flight ----
    ISSUE(0);
    WRITE(xa, wb);
    ISSUE(BK);             // tile 1 loads span the barrier + compute(0)
    __syncthreads();

    for (int k = 0; k < KSTEPS; ++k) {
        char* xcur = xa + (k & 1) * XTILE;
        char* xnxt = xa + ((k & 1) ^ 1) * XTILE;
        char* wcur = wb + (k & 1) * WTILE;
        char* wnxt = wb + ((k & 1) ^ 1) * WTILE;

        // compute current tile: 2 K=32 sub-steps x (2x4 frags, 8 MFMA)
#pragma unroll
        for (int ks = 0; ks < 2; ++ks) {
            short8 af[2], bfv[4];
#pragma unroll
            for (int m = 0; m < 2; ++m) {
                const int r = wrow + m * 16 + frow;
                af[m] = *(const short8*)(xcur + r * LSTRIDE + ks * 64 + kg * 2);
            }
#pragma unroll
            for (int n = 0; n < 4; ++n) {
                const int r = wcol + n * 16 + frow;
                bfv[n] = *(const short8*)(wcur + r * LSTRIDE + ks * 64 + kg * 2);
            }
#pragma unroll
            for (int m = 0; m < 2; ++m)
#pragma unroll
                for (int n = 0; n < 4; ++n)
                    acc[m][n] = __builtin_amdgcn_mfma_f32_16x16x32_bf16(
                        af[m], bfv[n], acc[m][n], 0, 0, 0);
        }

        // stage tile k+1 (loads issued one full iteration ago)
        if (k < KSTEPS - 1) WRITE(xnxt, wnxt);
        // re-issue into the just-freed regs: tile k+2 spans barrier+compute
        if (k < KSTEPS - 2) ISSUE((k + 2) * BK);
        __syncthreads();
    }
#undef ISSUE
#undef WRITE

    // epilogue: bias + relu -> LDS stash only
    // (C/D: col=lane&15, row=(lane>>4)*4+reg)
    float bv[4];
#pragma unroll
    for (int n = 0; n < 4; ++n) bv[n] = bias[wcol + n * 16 + frow];
    const int colb = wcol + frow;
    const int lrow0 = wrow + ((lane >> 4) * 4);
#pragma unroll
    for (int m = 0; m < 2; ++m)
#pragma unroll
        for (int j = 0; j < 4; ++j) {
            float* srow = stash + (lrow0 + m * 16 + j) * SSTRIDE;
#pragma unroll
            for (int n = 0; n < 4; ++n)
                srow[colb + n * 16] = fmaxf(acc[m][n][j] + bv[n], 0.0f);
        }
    __syncthreads();

    // ---- coalesced nt store phase: 2 panels x 4 f32x4/thread ----------------
    // Panel p covers stash rows p*64..p*64+63 -> global rows (p?row0s:row0f)+
    // 0..63 (linear). f32x4 index i in [0,2048): row=i>>5, chunk=i&31.
#pragma unroll
    for (int p = 0; p < 2; ++p) {
        float* gbase = out + ((p == 0) ? row0f : row0s) * N_DIM;
#pragma unroll
        for (int c = 0; c < 4; ++c) {
            const int i = c * 512 + tid;
            const int rowp = i >> 5;
            f32x4 v = *(const f32x4*)(stash + (p * 64 + rowp) * SSTRIDE + (i & 31) * 4);
            __builtin_nontemporal_store(v, (f32x4*)(gbase + i * 4));
        }
    }

    // ---- in-block MMD over the 32 pairs, reading the LDS stash -------------
    // (no barrier needed: stores above don't modify the stash)
    const int pr  = tid >> 4;      // pair 0..31
    const int sub = tid & 15;      // 16 threads/pair, 8 dims each
    const float* r0p = stash + (2 * pr) * SSTRIDE + sub * 8;        // s0
    const float* r1p = r0p + SSTRIDE;                               // s1
    const float* r2p = stash + (64 + 2 * pr) * SSTRIDE + sub * 8;   // t0
    const float* r3p = r2p + SSTRIDE;                               // t1

    f32x4 vss = (f32x4)(0.f), vtt = (f32x4)(0.f), vst = (f32x4)(0.f), vts = (f32x4)(0.f);
#pragma unroll
    for (int c = 0; c < 2; ++c) {
        f32x4 a0 = *(const f32x4*)(r0p + 4 * c);
        f32x4 a1 = *(const f32x4*)(r1p + 4 * c);
        f32x4 b0 = *(const f32x4*)(r2p + 4 * c);
        f32x4 b1 = *(const f32x4*)(r3p + 4 * c);
        f32x4 d;
        d = a0 - a1; vss += d * d;
        d = b0 - b1; vtt += d * d;
        d = a0 - b1; vst += d * d;
        d = a1 - b0; vts += d * d;
    }
    float D[4];
    D[0] = vss[0] + vss[1] + vss[2] + vss[3];
    D[1] = vtt[0] + vtt[1] + vtt[2] + vtt[3];
    D[2] = vst[0] + vst[1] + vst[2] + vst[3];
    D[3] = vts[0] + vts[1] + vts[2] + vts[3];
#pragma unroll
    for (int off = 1; off <= 8; off <<= 1) {
#pragma unroll
        for (int i = 0; i < 4; ++i) D[i] += __shfl_xor(D[i], off, 64);
    }
    // 32 signed exp terms spread over the 16 threads of the pair (2 each)
    float part = 0.f;
#pragma unroll
    for (int j = 0; j < 2; ++j) {
        const int t  = sub * 2 + j;      // 0..31
        const int di = t >> 3;           // distance index 0..3
        const float invg = 16.0f / (float)(1 << (t & 7));   // 1/gamma_k
        const float e = __expf(-D[di] * invg);
        part += (di < 2) ? e : -e;
    }
#pragma unroll
    for (int off = 1; off <= 8; off <<= 1) part += __shfl_xor(part, off, 64);
    if (sub == 0) gsh[pr] = part * 0.125f;
    __syncthreads();
    if (tid == 0) {
        double s = 0.0;
#pragma unroll
        for (int i = 0; i < 32; ++i) s += (double)gsh[i];
        partials[blk] = s;
    }
}

__global__ void __launch_bounds__(256) mmd_reduce_kernel(
    const double* __restrict__ partials, float* __restrict__ loss)
{
    __shared__ double sd[256];
    const int tid = threadIdx.x;
    double s = 0.0;
    for (int i = tid; i < GBLOCKS; i += 256) s += partials[i];
    sd[tid] = s;
    __syncthreads();
    for (int w = 128; w; w >>= 1) {
        if (tid < w) sd[tid] += sd[tid + w];
        __syncthreads();
    }
    if (tid == 0) loss[0] = (float)(sd[0] * (2.0 / 65536.0));
}

extern "C" void kernel_launch(void* const* d_in, const int* in_sizes, int n_in,
                              void* d_out, int out_size, void* d_ws, size_t ws_size,
                              hipStream_t stream) {
    const float* x = (const float*)d_in[0];
    const float* W = (const float*)d_in[1];
    const float* b = (const float*)d_in[2];
    float* out = (float*)d_out;                         // 131072*128 + 1 floats

    __hip_bfloat16* Wt = (__hip_bfloat16*)d_ws;                 // 128 KB
    double* partials = (double*)((char*)d_ws + 131072);         // 8 KB

    wt_prep_kernel<<<256, 256, 0, stream>>>(W, Wt);
    gemm_relu_mmd_kernel<<<GBLOCKS, 512, 0, stream>>>(x, Wt, b, out, partials);
    mmd_reduce_kernel<<<1, 256, 0, stream>>>(partials, out + (long)M_TOTAL * N_DIM);
}

// Round 19
// 68.845 us; speedup vs baseline: 1.0050x; 1.0050x over previous
//
#include <hip/hip_runtime.h>
#include <hip/hip_bf16.h>

typedef __attribute__((ext_vector_type(8))) short short8;
typedef __attribute__((ext_vector_type(4))) float f32x4;

#define M_TOTAL 131072
#define K_DIM 512
#define N_DIM 128
#define BM 128
#define BK 64
#define HALF 65536
#define GBLOCKS 1024
#define KSTEPS 8

// 64 bf16 = 128 B data + 16 B pad = 144 B rows; 144*r mod 128 walks all
// eight 16B slots across 8 rows -> conflict-benign, 16B-aligned for b128.
#define LSTRIDE 144
#define XTILE (BM * LSTRIDE)         // 18432 B
#define WTILE (N_DIM * LSTRIDE)      // 18432 B
// post-k-loop stash: 128 rows x 132 floats (528 B, bank-staggered)
#define SSTRIDE 132

__device__ __forceinline__ short bf16_bits(float f) {
    __hip_bfloat16 h = __float2bfloat16(f);
    return __builtin_bit_cast(short, h);
}

__device__ __forceinline__ short8 cvt8(f32x4 a, f32x4 b) {
    short8 p;
    p[0] = bf16_bits(a[0]); p[1] = bf16_bits(a[1]);
    p[2] = bf16_bits(a[2]); p[3] = bf16_bits(a[3]);
    p[4] = bf16_bits(b[0]); p[5] = bf16_bits(b[1]);
    p[6] = bf16_bits(b[2]); p[7] = bf16_bits(b[3]);
    return p;
}

// ---------------- W -> W^T bf16 prep ----------------------------------------
__global__ void __launch_bounds__(256) wt_prep_kernel(
    const float* __restrict__ W, __hip_bfloat16* __restrict__ Wt)
{
    int idx = blockIdx.x * 256 + threadIdx.x;   // 65536 total
    int k = idx >> 7;        // 0..511
    int n = idx & 127;       // 0..127
    Wt[n * K_DIM + k] = __float2bfloat16(W[idx]);
}

// ---- fused: relu(x@W+b) + MMD-from-LDS-stash; nontemporal out stores ------
// Final champion structure (R17):
//  * 8 waves x (32x64) sub-tiles, BK=64 (8 k-steps, halved barrier drains)
//  * cross-barrier load issue: ISSUE(k+2) right after WRITE(k+1) -> load
//    latency spans a full iteration + barrier (R15, -3us)
//  * epilogue stashes the relu'd tile in dead LDS; MMD reads LDS (R16)
//  * out is therefore write-only -> nontemporal stores preserve x's L3
//    residency across graph replays (R17, -10us)
__global__ void __launch_bounds__(512) gemm_relu_mmd_kernel(
    const float* __restrict__ x, const __hip_bfloat16* __restrict__ Wt,
    const float* __restrict__ bias, float* __restrict__ out,
    double* __restrict__ partials)
{
    __shared__ char pool[2 * XTILE + 2 * WTILE];   // 73728 B -> 2 blocks/CU
    char* xa = pool;                  // x tile t at pool + (t&1)*XTILE
    char* wb = pool + 2 * XTILE;      // W tile t at wb   + (t&1)*WTILE
    // post-k-loop aliases (whole pool dead after last barrier):
    float* stash = (float*)pool;              // [128][SSTRIDE] = 67584 B
    float* gsh   = (float*)(pool + 67584);    // 32 pair partials

    const int tid  = threadIdx.x;
    const int lane = tid & 63;
    const int wave = tid >> 6;          // 0..7: 4 row-groups x 2 col-groups
    const int wrow = (wave & 3) * 32;   // local rows wrow..wrow+31
    const int wcol = (wave >> 2) * 64;  // cols wcol..wcol+63
    const long blk = blockIdx.x;
    const long row0f = blk * 64;                 // first-half base
    const long row0s = (long)HALF + blk * 64;    // second-half base

    f32x4 acc[2][4];
#pragma unroll
    for (int m = 0; m < 2; ++m)
#pragma unroll
        for (int n = 0; n < 4; ++n) acc[m][n] = (f32x4)(0.0f);

    // staging: 512 threads cover 128 rows x 64 cols per tile
    const int sr  = tid >> 2;           // 0..127
    const int sby = (tid & 3) * 16;     // byte offset within 64B sub-window
    const long gr = (sr < 64) ? (row0f + sr) : (row0s + sr - 64);
    const float* xsrc = x + gr * (long)K_DIM + (tid & 3) * 8;
    const __hip_bfloat16* wsrc = Wt + (long)sr * K_DIM + (tid & 3) * 8;

    const int frow = lane & 15;
    const int kg   = (lane >> 4) * 8;

    f32x4 xr[2][2];   // [sub-stage][pair]
    short8 wr[2];

#define ISSUE(kt) do { \
        xr[0][0] = *(const f32x4*)(xsrc + (kt)); \
        xr[0][1] = *(const f32x4*)(xsrc + (kt) + 4); \
        xr[1][0] = *(const f32x4*)(xsrc + (kt) + 32); \
        xr[1][1] = *(const f32x4*)(xsrc + (kt) + 36); \
        wr[0] = *(const short8*)(wsrc + (kt)); \
        wr[1] = *(const short8*)(wsrc + (kt) + 32); \
    } while (0)

#define WRITE(xbuf, wbuf) do { \
        *(short8*)((xbuf) + sr * LSTRIDE + 0 * 64 + sby) = cvt8(xr[0][0], xr[0][1]); \
        *(short8*)((xbuf) + sr * LSTRIDE + 1 * 64 + sby) = cvt8(xr[1][0], xr[1][1]); \
        *(short8*)((wbuf) + sr * LSTRIDE + 0 * 64 + sby) = wr[0]; \
        *(short8*)((wbuf) + sr * LSTRIDE + 1 * 64 + sby) = wr[1]; \
    } while (0)

    // ---- prologue: stage tile 0 into buffer 0; tile 1's loads in flight ----
    ISSUE(0);
    WRITE(xa, wb);
    ISSUE(BK);             // tile 1 loads span the barrier + compute(0)
    __syncthreads();

    for (int k = 0; k < KSTEPS; ++k) {
        char* xcur = xa + (k & 1) * XTILE;
        char* xnxt = xa + ((k & 1) ^ 1) * XTILE;
        char* wcur = wb + (k & 1) * WTILE;
        char* wnxt = wb + ((k & 1) ^ 1) * WTILE;

        // compute current tile: 2 K=32 sub-steps x (2x4 frags, 8 MFMA)
#pragma unroll
        for (int ks = 0; ks < 2; ++ks) {
            short8 af[2], bfv[4];
#pragma unroll
            for (int m = 0; m < 2; ++m) {
                const int r = wrow + m * 16 + frow;
                af[m] = *(const short8*)(xcur + r * LSTRIDE + ks * 64 + kg * 2);
            }
#pragma unroll
            for (int n = 0; n < 4; ++n) {
                const int r = wcol + n * 16 + frow;
                bfv[n] = *(const short8*)(wcur + r * LSTRIDE + ks * 64 + kg * 2);
            }
#pragma unroll
            for (int m = 0; m < 2; ++m)
#pragma unroll
                for (int n = 0; n < 4; ++n)
                    acc[m][n] = __builtin_amdgcn_mfma_f32_16x16x32_bf16(
                        af[m], bfv[n], acc[m][n], 0, 0, 0);
        }

        // stage tile k+1 (loads issued one full iteration ago)
        if (k < KSTEPS - 1) WRITE(xnxt, wnxt);
        // re-issue into the just-freed regs: tile k+2 spans barrier+compute
        if (k < KSTEPS - 2) ISSUE((k + 2) * BK);
        __syncthreads();
    }
#undef ISSUE
#undef WRITE

    // epilogue: bias + relu -> nontemporal global store + LDS stash
    // (C/D: col=lane&15, row=(lane>>4)*4+reg)
    float bv[4];
#pragma unroll
    for (int n = 0; n < 4; ++n) bv[n] = bias[wcol + n * 16 + frow];
    const int colb = wcol + frow;
    const int lrow0 = wrow + ((lane >> 4) * 4);
    const long grow = ((wrow < 64) ? (row0f + wrow) : (row0s + wrow - 64))
                      + ((lane >> 4) * 4);
#pragma unroll
    for (int m = 0; m < 2; ++m)
#pragma unroll
        for (int j = 0; j < 4; ++j) {
            float* orow = out + (grow + m * 16 + j) * N_DIM;
            float* srow = stash + (lrow0 + m * 16 + j) * SSTRIDE;
#pragma unroll
            for (int n = 0; n < 4; ++n) {
                const float v = fmaxf(acc[m][n][j] + bv[n], 0.0f);
                __builtin_nontemporal_store(v, &orow[colb + n * 16]);
                srow[colb + n * 16] = v;
            }
        }

    // ---- in-block MMD over the 32 pairs, reading the LDS stash -------------
    __syncthreads();

    const int pr  = tid >> 4;      // pair 0..31
    const int sub = tid & 15;      // 16 threads/pair, 8 dims each
    const float* r0p = stash + (2 * pr) * SSTRIDE + sub * 8;        // s0
    const float* r1p = r0p + SSTRIDE;                               // s1
    const float* r2p = stash + (64 + 2 * pr) * SSTRIDE + sub * 8;   // t0
    const float* r3p = r2p + SSTRIDE;                               // t1

    f32x4 vss = (f32x4)(0.f), vtt = (f32x4)(0.f), vst = (f32x4)(0.f), vts = (f32x4)(0.f);
#pragma unroll
    for (int c = 0; c < 2; ++c) {
        f32x4 a0 = *(const f32x4*)(r0p + 4 * c);
        f32x4 a1 = *(const f32x4*)(r1p + 4 * c);
        f32x4 b0 = *(const f32x4*)(r2p + 4 * c);
        f32x4 b1 = *(const f32x4*)(r3p + 4 * c);
        f32x4 d;
        d = a0 - a1; vss += d * d;
        d = b0 - b1; vtt += d * d;
        d = a0 - b1; vst += d * d;
        d = a1 - b0; vts += d * d;
    }
    float D[4];
    D[0] = vss[0] + vss[1] + vss[2] + vss[3];
    D[1] = vtt[0] + vtt[1] + vtt[2] + vtt[3];
    D[2] = vst[0] + vst[1] + vst[2] + vst[3];
    D[3] = vts[0] + vts[1] + vts[2] + vts[3];
#pragma unroll
    for (int off = 1; off <= 8; off <<= 1) {
#pragma unroll
        for (int i = 0; i < 4; ++i) D[i] += __shfl_xor(D[i], off, 64);
    }
    // 32 signed exp terms spread over the 16 threads of the pair (2 each)
    float part = 0.f;
#pragma unroll
    for (int j = 0; j < 2; ++j) {
        const int t  = sub * 2 + j;      // 0..31
        const int di = t >> 3;           // distance index 0..3
        const float invg = 16.0f / (float)(1 << (t & 7));   // 1/gamma_k
        const float e = __expf(-D[di] * invg);
        part += (di < 2) ? e : -e;
    }
#pragma unroll
    for (int off = 1; off <= 8; off <<= 1) part += __shfl_xor(part, off, 64);
    if (sub == 0) gsh[pr] = part * 0.125f;
    __syncthreads();
    if (tid == 0) {
        double s = 0.0;
#pragma unroll
        for (int i = 0; i < 32; ++i) s += (double)gsh[i];
        partials[blk] = s;
    }
}

__global__ void __launch_bounds__(256) mmd_reduce_kernel(
    const double* __restrict__ partials, float* __restrict__ loss)
{
    __shared__ double sd[256];
    const int tid = threadIdx.x;
    double s = 0.0;
    for (int i = tid; i < GBLOCKS; i += 256) s += partials[i];
    sd[tid] = s;
    __syncthreads();
    for (int w = 128; w; w >>= 1) {
        if (tid < w) sd[tid] += sd[tid + w];
        __syncthreads();
    }
    if (tid == 0) loss[0] = (float)(sd[0] * (2.0 / 65536.0));
}

extern "C" void kernel_launch(void* const* d_in, const int* in_sizes, int n_in,
                              void* d_out, int out_size, void* d_ws, size_t ws_size,
                              hipStream_t stream) {
    const float* x = (const float*)d_in[0];
    const float* W = (const float*)d_in[1];
    const float* b = (const float*)d_in[2];
    float* out = (float*)d_out;                         // 131072*128 + 1 floats

    __hip_bfloat16* Wt = (__hip_bfloat16*)d_ws;                 // 128 KB
    double* partials = (double*)((char*)d_ws + 131072);         // 8 KB

    wt_prep_kernel<<<256, 256, 0, stream>>>(W, Wt);
    gemm_relu_mmd_kernel<<<GBLOCKS, 512, 0, stream>>>(x, Wt, b, out, partials);
    mmd_reduce_kernel<<<1, 256, 0, stream>>>(partials, out + (long)M_TOTAL * N_DIM);
}